// Round 8
// baseline (195.877 us; speedup 1.0000x reference)
//
#include <hip/hip_runtime.h>

// B=2, S=2048, H=1024, NH=16, HD=64. f32 in/out; bf16 intermediates + MFMA.
// MFMA 16x16x32 bf16 layouts (m89/m91):
//   A: lane holds A[m=lane&15][k=quad*8+j]   B: B[k=quad*8+j][n=lane&15]
//   C/D: lane reg r -> row=quad*4+r, col=lane&15
typedef __bf16 bf16;
typedef __bf16 bf16x4 __attribute__((ext_vector_type(4)));
typedef __bf16 bf16x8 __attribute__((ext_vector_type(8)));
typedef float floatx4 __attribute__((ext_vector_type(4)));

#define MFMA16(a, b, c) __builtin_amdgcn_mfma_f32_16x16x32_bf16(a, b, c, 0, 0, 0)

__device__ __forceinline__ void load_lds16(const void* g, void* l) {
    // async global->LDS DMA, 16B/lane; dest = wave-uniform base + lane*16
    __builtin_amdgcn_global_load_lds(
        (const __attribute__((address_space(1))) unsigned int*)g,
        (__attribute__((address_space(3))) unsigned int*)l, 16, 0, 0);
}

__device__ __forceinline__ bf16x8 scale8(bf16x8 a, float s) {
    bf16x8 o;
    #pragma unroll
    for (int i = 0; i < 8; i++) o[i] = (bf16)((float)a[i] * s);
    return o;
}

// counted-vmcnt barrier pair (T3+T4): loads stay in flight across barriers.
#define WAITV4_BAR()  do { asm volatile("s_waitcnt vmcnt(4)" ::: "memory"); \
                           __builtin_amdgcn_s_barrier();                    \
                           __builtin_amdgcn_sched_barrier(0); } while (0)
#define WAITV0_BAR()  do { asm volatile("s_waitcnt vmcnt(0)" ::: "memory"); \
                           __builtin_amdgcn_s_barrier();                    \
                           __builtin_amdgcn_sched_barrier(0); } while (0)
#define TRAIL_BAR()   do { __builtin_amdgcn_sched_barrier(0);               \
                           asm volatile("s_waitcnt lgkmcnt(0)" ::: "memory"); \
                           __builtin_amdgcn_s_barrier(); } while (0)

// ---------------------------------------------------------------------------
// cvt: x (4096 blk), Wq/Wk/Wv/Wo (1024 blk each) f32 -> bf16
// ---------------------------------------------------------------------------
__global__ __launch_bounds__(256) void cvt_all_kernel(
    const float* __restrict__ x, const float* __restrict__ wq,
    const float* __restrict__ wk, const float* __restrict__ wv,
    const float* __restrict__ wo,
    bf16* __restrict__ xb, bf16* __restrict__ wqb, bf16* __restrict__ wkb,
    bf16* __restrict__ wvb, bf16* __restrict__ wob)
{
    int bid = blockIdx.x;
    const float* src; bf16* dst; int off;
    if (bid < 4096)      { src = x;  dst = xb;  off = bid; }
    else if (bid < 5120) { src = wq; dst = wqb; off = bid - 4096; }
    else if (bid < 6144) { src = wk; dst = wkb; off = bid - 5120; }
    else if (bid < 7168) { src = wv; dst = wvb; off = bid - 6144; }
    else                 { src = wo; dst = wob; off = bid - 7168; }
    int idx = (off * 256 + threadIdx.x) * 4;
    float4 v = *(const float4*)&src[idx];
    bf16x4 o;
    o[0] = (bf16)v.x; o[1] = (bf16)v.y; o[2] = (bf16)v.z; o[3] = (bf16)v.w;
    *(bf16x4*)&dst[idx] = o;
}

__global__ __launch_bounds__(256) void cvt_kernel(const float* __restrict__ x,
                                                  bf16* __restrict__ xb) {
    int idx = (blockIdx.x * 256 + threadIdx.x) * 4;
    float4 v = *(const float4*)&x[idx];
    bf16x4 o;
    o[0] = (bf16)v.x; o[1] = (bf16)v.y; o[2] = (bf16)v.z; o[3] = (bf16)v.w;
    *(bf16x4*)&xb[idx] = o;
}

// ===========================================================================
// FAST GEMMs V3: 2-phase BK=32 ping-pong with COUNTED vmcnt (T3+T4) + T5.
// (unchanged from round 4 — verified fast)
// ===========================================================================

#define PREP_STAGE()                                                          \
    int u0 = w * 128 + lane;                                                  \
    int u1 = u0 + 64;                                                         \
    int r0_ = u0 >> 2, c0_ = ((u0 & 3) ^ ((r0_ >> 1) & 3)) * 8;               \
    int r1_ = u1 >> 2, c1_ = ((u1 & 3) ^ ((r1_ >> 1) & 3)) * 8;               \
    int du0 = w * 1024;                                                       \
    int du1 = du0 + 512;

#define STAGE_PF(Asrc, Bsrc, arow, brow, sbuf, kk0)                           \
    do {                                                                      \
        load_lds16(&Asrc[(size_t)((arow) + r0_) * 1024 + (kk0) + c0_],        \
                   &As[sbuf][0][0] + du0);                                    \
        load_lds16(&Asrc[(size_t)((arow) + r1_) * 1024 + (kk0) + c1_],        \
                   &As[sbuf][0][0] + du1);                                    \
        load_lds16(&Bsrc[(size_t)((brow) + r0_) * 1024 + (kk0) + c0_],        \
                   &Bs[sbuf][0][0] + du0);                                    \
        load_lds16(&Bsrc[(size_t)((brow) + r1_) * 1024 + (kk0) + c1_],        \
                   &Bs[sbuf][0][0] + du1);                                    \
    } while (0)

#define GEMM_CORE(Asrc, Bsrc, arow, brow)                                     \
    PREP_STAGE()                                                              \
    STAGE_PF(Asrc, Bsrc, arow, brow, 0, 0);                                   \
    _Pragma("unroll 2")                                                       \
    for (int s = 0; s < 32; s++) {                                            \
        int sb = s & 1;                                                       \
        if (s + 1 < 32) {                                                     \
            STAGE_PF(Asrc, Bsrc, arow, brow, sb ^ 1, (s + 1) * 32);           \
            WAITV4_BAR();                                                     \
        } else {                                                              \
            WAITV0_BAR();                                                     \
        }                                                                     \
        bf16x8 af[4], bfr[4];                                                 \
        _Pragma("unroll")                                                     \
        for (int mt = 0; mt < 4; mt++) {                                      \
            int row = wm + mt * 16 + l15;                                     \
            af[mt] = *(const bf16x8*)&As[sb][row][(quad ^ ((row >> 1) & 3)) * 8]; \
        }                                                                     \
        _Pragma("unroll")                                                     \
        for (int nt = 0; nt < 4; nt++) {                                      \
            int row = wn + nt * 16 + l15;                                     \
            bfr[nt] = *(const bf16x8*)&Bs[sb][row][(quad ^ ((row >> 1) & 3)) * 8]; \
        }                                                                     \
        __builtin_amdgcn_s_setprio(1);                                        \
        _Pragma("unroll")                                                     \
        for (int mt = 0; mt < 4; mt++)                                        \
            _Pragma("unroll")                                                 \
            for (int nt = 0; nt < 4; nt++)                                    \
                acc[mt][nt] = MFMA16(af[mt], bfr[nt], acc[mt][nt]);           \
        __builtin_amdgcn_s_setprio(0);                                        \
        TRAIL_BAR();                                                          \
    }

// ---------------------------------------------------------------------------
// QKV projection + bias + fused RoPE (q,k) + transposed V store.
// q_ws,k_ws: (B,NH,S,HD); vt_ws: (B,NH,HD,S). All-bf16 inputs.
// ---------------------------------------------------------------------------
__global__ __launch_bounds__(256) void gemm_qkv_fast(
    const bf16* __restrict__ xb,
    const bf16* __restrict__ Wq, const bf16* __restrict__ Wk,
    const bf16* __restrict__ Wv,
    const float* __restrict__ bq, const float* __restrict__ bk,
    const float* __restrict__ bv,
    bf16* __restrict__ q_ws, bf16* __restrict__ k_ws, bf16* __restrict__ vt_ws)
{
    int m0 = blockIdx.x * 128;
    int n0 = blockIdx.y * 128;
    int sec = n0 >> 10;
    int nw0 = n0 & 1023;
    const bf16* W     = (sec == 0) ? Wq : (sec == 1) ? Wk : Wv;
    const float* bias = (sec == 0) ? bq : (sec == 1) ? bk : bv;

    __shared__ bf16 As[2][128][32];
    __shared__ bf16 Bs[2][128][32];

    int tid = threadIdx.x;
    int lane = tid & 63, w = tid >> 6;
    int l15 = lane & 15, quad = lane >> 4;
    int wm = (w >> 1) * 64, wn = (w & 1) * 64;

    floatx4 acc[4][4];
    #pragma unroll
    for (int i = 0; i < 4; i++)
        #pragma unroll
        for (int j = 0; j < 4; j++) acc[i][j] = (floatx4){0.f, 0.f, 0.f, 0.f};

    GEMM_CORE(xb, W, m0, nw0)

    if (sec < 2) {
        bf16* outp = (sec == 0) ? q_ws : k_ws;
        float inv[2];
        inv[0] = __expf(-(float)l15 * (9.210340371976184f / 32.0f));
        inv[1] = __expf(-(float)(16 + l15) * (9.210340371976184f / 32.0f));
        #pragma unroll
        for (int mt = 0; mt < 4; mt++) {
            #pragma unroll
            for (int r = 0; r < 4; r++) {
                int m = m0 + wm + mt * 16 + quad * 4 + r;
                int bb = m >> 11, s = m & 2047;
                #pragma unroll
                for (int nt = 0; nt < 2; nt++) {
                    int nl1 = nw0 + wn + nt * 16 + l15;
                    int nl2 = nl1 + 32;
                    float x1 = acc[mt][nt][r] + bias[nl1];
                    float x2 = acc[mt][nt + 2][r] + bias[nl2];
                    float ang = (float)s * inv[nt];
                    float sn, cs;
                    __sincosf(ang, &sn, &cs);
                    int hh = nl1 >> 6, d = nl1 & 63;
                    size_t base = ((size_t)(bb * 16 + hh) * 2048 + s) * 64;
                    outp[base + d]      = (bf16)(x1 * cs - x2 * sn);
                    outp[base + d + 32] = (bf16)(x2 * cs + x1 * sn);
                }
            }
        }
    } else {
        #pragma unroll
        for (int mt = 0; mt < 4; mt++) {
            int mbase = m0 + wm + mt * 16 + quad * 4;
            int bb = mbase >> 11, s0 = mbase & 2047;
            #pragma unroll
            for (int nt = 0; nt < 4; nt++) {
                int nl = nw0 + wn + nt * 16 + l15;
                int hh = nl >> 6, d = nl & 63;
                bf16x4 pk;
                #pragma unroll
                for (int r = 0; r < 4; r++) pk[r] = (bf16)(acc[mt][nt][r] + bias[nl]);
                *(bf16x4*)&vt_ws[((size_t)(bb * 16 + hh) * 64 + d) * 2048 + s0] = pk;
            }
        }
    }
}

// ---------------------------------------------------------------------------
// Output projection (fast): out[m][n] = sum_k O[m][k]*Wo[n][k] + bo[n]
// ---------------------------------------------------------------------------
__global__ __launch_bounds__(256) void gemm_out_fast(
    const bf16* __restrict__ A, const bf16* __restrict__ W,
    const float* __restrict__ bias, float* __restrict__ out)
{
    int m0 = blockIdx.x * 128;
    int n0 = blockIdx.y * 128;

    __shared__ bf16 As[2][128][32];
    __shared__ bf16 Bs[2][128][32];

    int tid = threadIdx.x;
    int lane = tid & 63, w = tid >> 6;
    int l15 = lane & 15, quad = lane >> 4;
    int wm = (w >> 1) * 64, wn = (w & 1) * 64;

    floatx4 acc[4][4];
    #pragma unroll
    for (int i = 0; i < 4; i++)
        #pragma unroll
        for (int j = 0; j < 4; j++) acc[i][j] = (floatx4){0.f, 0.f, 0.f, 0.f};

    GEMM_CORE(A, W, m0, n0)

    #pragma unroll
    for (int mt = 0; mt < 4; mt++) {
        #pragma unroll
        for (int r = 0; r < 4; r++) {
            int m = m0 + wm + mt * 16 + quad * 4 + r;
            #pragma unroll
            for (int nt = 0; nt < 4; nt++) {
                int nl = n0 + wn + nt * 16 + l15;
                out[(size_t)m * 1024 + nl] = acc[mt][nt][r] + bias[nl];
            }
        }
    }
}

// ===========================================================================
// FALLBACK GEMMs (f32 W staged with in-flight cvt) — used if ws too small
// ===========================================================================
__global__ __launch_bounds__(256) void gemm_qkv_f32w(
    const bf16* __restrict__ xb,
    const float* __restrict__ Wq, const float* __restrict__ Wk,
    const float* __restrict__ Wv,
    const float* __restrict__ bq, const float* __restrict__ bk,
    const float* __restrict__ bv,
    bf16* __restrict__ q_ws, bf16* __restrict__ k_ws, bf16* __restrict__ vt_ws)
{
    int m0 = blockIdx.x * 128;
    int n0 = blockIdx.y * 128;
    int sec = n0 >> 10;
    int nw0 = n0 & 1023;
    const float* W    = (sec == 0) ? Wq : (sec == 1) ? Wk : Wv;
    const float* bias = (sec == 0) ? bq : (sec == 1) ? bk : bv;

    __shared__ bf16 As[128][72];
    __shared__ bf16 Bs[128][72];

    int tid = threadIdx.x;
    int lane = tid & 63, w = tid >> 6;
    int l15 = lane & 15, quad = lane >> 4;
    int wm = (w >> 1) * 64, wn = (w & 1) * 64;
    int sr = tid >> 1;
    int sk = (tid & 1) * 32;

    floatx4 acc[4][4];
    #pragma unroll
    for (int i = 0; i < 4; i++)
        #pragma unroll
        for (int j = 0; j < 4; j++) acc[i][j] = (floatx4){0.f, 0.f, 0.f, 0.f};

    for (int k0 = 0; k0 < 1024; k0 += 64) {
        __syncthreads();
        const bf16* ap = &xb[(size_t)(m0 + sr) * 1024 + k0 + sk];
        bf16x8 a0 = *(const bf16x8*)(ap);
        bf16x8 a1 = *(const bf16x8*)(ap + 8);
        bf16x8 a2 = *(const bf16x8*)(ap + 16);
        bf16x8 a3 = *(const bf16x8*)(ap + 24);
        const float* wp = &W[(size_t)(nw0 + sr) * 1024 + k0 + sk];
        bf16x8 bv_[4];
        #pragma unroll
        for (int c = 0; c < 4; c++) {
            float4 f0 = *(const float4*)(wp + c * 8);
            float4 f1 = *(const float4*)(wp + c * 8 + 4);
            bf16x8 t;
            t[0] = (bf16)f0.x; t[1] = (bf16)f0.y; t[2] = (bf16)f0.z; t[3] = (bf16)f0.w;
            t[4] = (bf16)f1.x; t[5] = (bf16)f1.y; t[6] = (bf16)f1.z; t[7] = (bf16)f1.w;
            bv_[c] = t;
        }
        *(bf16x8*)&As[sr][sk + 0]  = a0;
        *(bf16x8*)&As[sr][sk + 8]  = a1;
        *(bf16x8*)&As[sr][sk + 16] = a2;
        *(bf16x8*)&As[sr][sk + 24] = a3;
        #pragma unroll
        for (int c = 0; c < 4; c++) *(bf16x8*)&Bs[sr][sk + c * 8] = bv_[c];
        __syncthreads();
        #pragma unroll
        for (int kk = 0; kk < 64; kk += 32) {
            bf16x8 af[4], bfr[4];
            #pragma unroll
            for (int mt = 0; mt < 4; mt++)
                af[mt] = *(const bf16x8*)&As[wm + mt * 16 + l15][kk + quad * 8];
            #pragma unroll
            for (int nt = 0; nt < 4; nt++)
                bfr[nt] = *(const bf16x8*)&Bs[wn + nt * 16 + l15][kk + quad * 8];
            #pragma unroll
            for (int mt = 0; mt < 4; mt++)
                #pragma unroll
                for (int nt = 0; nt < 4; nt++)
                    acc[mt][nt] = MFMA16(af[mt], bfr[nt], acc[mt][nt]);
        }
    }

    if (sec < 2) {
        bf16* outp = (sec == 0) ? q_ws : k_ws;
        float inv[2];
        inv[0] = __expf(-(float)l15 * (9.210340371976184f / 32.0f));
        inv[1] = __expf(-(float)(16 + l15) * (9.210340371976184f / 32.0f));
        #pragma unroll
        for (int mt = 0; mt < 4; mt++) {
            #pragma unroll
            for (int r = 0; r < 4; r++) {
                int m = m0 + wm + mt * 16 + quad * 4 + r;
                int bb = m >> 11, s = m & 2047;
                #pragma unroll
                for (int nt = 0; nt < 2; nt++) {
                    int nl1 = nw0 + wn + nt * 16 + l15;
                    int nl2 = nl1 + 32;
                    float x1 = acc[mt][nt][r] + bias[nl1];
                    float x2 = acc[mt][nt + 2][r] + bias[nl2];
                    float ang = (float)s * inv[nt];
                    float sn, cs;
                    __sincosf(ang, &sn, &cs);
                    int hh = nl1 >> 6, d = nl1 & 63;
                    size_t base = ((size_t)(bb * 16 + hh) * 2048 + s) * 64;
                    outp[base + d]      = (bf16)(x1 * cs - x2 * sn);
                    outp[base + d + 32] = (bf16)(x2 * cs + x1 * sn);
                }
            }
        }
    } else {
        #pragma unroll
        for (int mt = 0; mt < 4; mt++) {
            int mbase = m0 + wm + mt * 16 + quad * 4;
            int bb = mbase >> 11, s0 = mbase & 2047;
            #pragma unroll
            for (int nt = 0; nt < 4; nt++) {
                int nl = nw0 + wn + nt * 16 + l15;
                int hh = nl >> 6, d = nl & 63;
                bf16x4 pk;
                #pragma unroll
                for (int r = 0; r < 4; r++) pk[r] = (bf16)(acc[mt][nt][r] + bias[nl]);
                *(bf16x4*)&vt_ws[((size_t)(bb * 16 + hh) * 64 + d) * 2048 + s0] = pk;
            }
        }
    }
}

__global__ __launch_bounds__(256) void gemm_out_f32w(
    const bf16* __restrict__ A, const float* __restrict__ W,
    const float* __restrict__ bias, float* __restrict__ out)
{
    int m0 = blockIdx.x * 128;
    int n0 = blockIdx.y * 128;

    __shared__ bf16 As[128][72];
    __shared__ bf16 Bs[128][72];

    int tid = threadIdx.x;
    int lane = tid & 63, w = tid >> 6;
    int l15 = lane & 15, quad = lane >> 4;
    int wm = (w >> 1) * 64, wn = (w & 1) * 64;
    int sr = tid >> 1;
    int sk = (tid & 1) * 32;

    floatx4 acc[4][4];
    #pragma unroll
    for (int i = 0; i < 4; i++)
        #pragma unroll
        for (int j = 0; j < 4; j++) acc[i][j] = (floatx4){0.f, 0.f, 0.f, 0.f};

    for (int k0 = 0; k0 < 1024; k0 += 64) {
        __syncthreads();
        const bf16* ap = &A[(size_t)(m0 + sr) * 1024 + k0 + sk];
        bf16x8 a0 = *(const bf16x8*)(ap);
        bf16x8 a1 = *(const bf16x8*)(ap + 8);
        bf16x8 a2 = *(const bf16x8*)(ap + 16);
        bf16x8 a3 = *(const bf16x8*)(ap + 24);
        const float* wp = &W[(size_t)(n0 + sr) * 1024 + k0 + sk];
        bf16x8 bv_[4];
        #pragma unroll
        for (int c = 0; c < 4; c++) {
            float4 f0 = *(const float4*)(wp + c * 8);
            float4 f1 = *(const float4*)(wp + c * 8 + 4);
            bf16x8 t;
            t[0] = (bf16)f0.x; t[1] = (bf16)f0.y; t[2] = (bf16)f0.z; t[3] = (bf16)f0.w;
            t[4] = (bf16)f1.x; t[5] = (bf16)f1.y; t[6] = (bf16)f1.z; t[7] = (bf16)f1.w;
            bv_[c] = t;
        }
        *(bf16x8*)&As[sr][sk + 0]  = a0;
        *(bf16x8*)&As[sr][sk + 8]  = a1;
        *(bf16x8*)&As[sr][sk + 16] = a2;
        *(bf16x8*)&As[sr][sk + 24] = a3;
        #pragma unroll
        for (int c = 0; c < 4; c++) *(bf16x8*)&Bs[sr][sk + c * 8] = bv_[c];
        __syncthreads();
        #pragma unroll
        for (int kk = 0; kk < 64; kk += 32) {
            bf16x8 af[4], bfr[4];
            #pragma unroll
            for (int mt = 0; mt < 4; mt++)
                af[mt] = *(const bf16x8*)&As[wm + mt * 16 + l15][kk + quad * 8];
            #pragma unroll
            for (int nt = 0; nt < 4; nt++)
                bfr[nt] = *(const bf16x8*)&Bs[wn + nt * 16 + l15][kk + quad * 8];
            #pragma unroll
            for (int mt = 0; mt < 4; mt++)
                #pragma unroll
                for (int nt = 0; nt < 4; nt++)
                    acc[mt][nt] = MFMA16(af[mt], bfr[nt], acc[mt][nt]);
        }
    }

    #pragma unroll
    for (int mt = 0; mt < 4; mt++) {
        #pragma unroll
        for (int r = 0; r < 4; r++) {
            int m = m0 + wm + mt * 16 + quad * 4 + r;
            #pragma unroll
            for (int nt = 0; nt < 4; nt++) {
                int nl = n0 + wn + nt * 16 + l15;
                out[(size_t)m * 1024 + nl] = acc[mt][nt][r] + bias[nl];
            }
        }
    }
}

// ---------------------------------------------------------------------------
// MFMA flash attention V8: V7 + 4 BLOCKS/CU.
// Round-7 lesson: LDS 41984B capped residency at 3 blocks/CU (occupancy 24%).
// V8: Ps 9216->8192B via chunk-XOR swizzle ([4][16][64]; write b64 at chunk
// (2kb+(quad>>1))^(l15&7), read b128 at chunk quad^(l15&7) — same bank spread
// as the padded layout). Total LDS = 32768+8192 = 40960 = exactly 160KB/4.
// Per-CU balance for 4 residents: co-resident x set {x0,x0+8,x0+16,x0+24}
// maps to qt {x0,15-x0,16+x0,31-x0} -> every CU sums 66 iters.
// Staging uses running pointers (+8KB K, +128B V per tile) — no per-iter
// 64-bit address recompute. Rest identical to V7 (counted-vmcnt ping-pong,
// XCD swizzle, fixed-max softmax, setprio).
// ---------------------------------------------------------------------------
__global__ __launch_bounds__(256, 4) void attn_kernel(
    const bf16* __restrict__ q_ws, const bf16* __restrict__ k_ws,
    const bf16* __restrict__ vt_ws, bf16* __restrict__ o_ws)
{
    __shared__ bf16 Ks[2][64][64];   // [buf][key][d], chunk-swizzled
    __shared__ bf16 Vt[2][64][64];   // [buf][d][key], chunk-swizzled
    __shared__ bf16 Ps[4][16][64];   // per-wave P [q][key], chunk-XOR swizzled

    int tid = threadIdx.x;
    int w = tid >> 6, lane = tid & 63;
    int l15 = lane & 15, quad = lane >> 4;

    int bid = blockIdx.x;            // 0..1023
    int g = bid & 31;                // bh; bid%8==g%8 -> same XCD per bh
    int x = bid >> 5;                // 0..31
    // balanced bijection: co-resident {x0,x0+8,x0+16,x0+24} -> qt sums 62
    int qt = (x < 8) ? x : (x < 16) ? 23 - x : (x < 24) ? x : 55 - x;
    int bb = g >> 4, h = g & 15;
    const bf16* qp = q_ws + (size_t)g * 2048 * 64;
    const bf16* kp = k_ws + (size_t)g * 2048 * 64;
    const bf16* vp = vt_ws + (size_t)g * 64 * 2048;
    int qrow = qt * 64 + w * 16;

    // staging map: wave w stages segments {2w,2w+1} (16 rows) of K and V.
    int g0 = (w * 2) * 64 + lane;
    int g1 = g0 + 64;
    int r0 = g0 >> 3, c0 = (g0 & 7) ^ (r0 & 7);
    int r1 = g1 >> 3, c1 = (g1 & 7) ^ (r1 & 7);
    int o0 = (w * 2) * 512;          // bf16 offset of wave's segment 0
    int o1 = o0 + 512;

    // running stage-source pointers (advance: K +4096 elems, V +64 elems/tile)
    const bf16* kst0 = kp + (size_t)r0 * 64 + c0 * 8;
    const bf16* kst1 = kp + (size_t)r1 * 64 + c1 * 8;
    const bf16* vst0 = vp + (size_t)r0 * 2048 + c0 * 8;
    const bf16* vst1 = vp + (size_t)r1 * 2048 + c1 * 8;

    const float SCL = 0.125f * 1.4426950408889634f;   // (1/sqrt(HD))*log2(e)
    const float MFIX = 20.0f;        // fixed exp2-domain shift (folded in C-init)

    // Q B-frags resident, pre-scaled
    bf16x8 qf0 = scale8(*(const bf16x8*)&qp[(size_t)(qrow + l15) * 64 + quad * 8], SCL);
    bf16x8 qf1 = scale8(*(const bf16x8*)&qp[(size_t)(qrow + l15) * 64 + 32 + quad * 8], SCL);

    float l_lane = 0.f;
    floatx4 acc[4];
    #pragma unroll
    for (int nt = 0; nt < 4; nt++) acc[nt] = (floatx4){0.f, 0.f, 0.f, 0.f};

    int nkt = qt + 1;                // key tiles 0..qt cover q-tile qt
    int lx7 = l15 & 7;               // Ps swizzle key

    // prologue: stage kt=0 into buf 0
    load_lds16(kst0, &Ks[0][0][0] + o0);
    load_lds16(kst1, &Ks[0][0][0] + o1);
    load_lds16(vst0, &Vt[0][0][0] + o0);
    load_lds16(vst1, &Vt[0][0][0] + o1);
    kst0 += 4096; kst1 += 4096; vst0 += 64; vst1 += 64;

    for (int kt = 0; kt < nkt; kt++) {
        int buf = kt & 1;
        // issue prefetch kt+1 into buf^1, then counted publish of buf
        if (kt + 1 < nkt) {
            load_lds16(kst0, &Ks[buf ^ 1][0][0] + o0);
            load_lds16(kst1, &Ks[buf ^ 1][0][0] + o1);
            load_lds16(vst0, &Vt[buf ^ 1][0][0] + o0);
            load_lds16(vst1, &Vt[buf ^ 1][0][0] + o1);
            kst0 += 4096; kst1 += 4096; vst0 += 64; vst1 += 64;
            WAITV4_BAR();
        } else {
            WAITV0_BAR();
        }

        int kt0 = kt * 64;

        // S^T = K * Q^T : per lane 4 keys (quad*4+r) x 1 query (l15).
        floatx4 st[4];
        #pragma unroll
        for (int kb = 0; kb < 4; kb++) {
            int row = kb * 16 + l15;
            int rx = row & 7;
            bf16x8 a0 = *(const bf16x8*)&Ks[buf][row][(quad ^ rx) * 8];
            bf16x8 a1 = *(const bf16x8*)&Ks[buf][row][((quad + 4) ^ rx) * 8];
            floatx4 z = {-MFIX, -MFIX, -MFIX, -MFIX};
            __builtin_amdgcn_s_setprio(1);
            z = MFMA16(a0, qf0, z);
            z = MFMA16(a1, qf1, z);
            __builtin_amdgcn_s_setprio(0);
            st[kb] = z;
        }
        if (kt0 + 63 > qrow) {   // diagonal/above tile for this wave: causal mask
            int q = qrow + l15;
            #pragma unroll
            for (int kb = 0; kb < 4; kb++)
                #pragma unroll
                for (int rr = 0; rr < 4; rr++) {
                    int key = kt0 + kb * 16 + quad * 4 + rr;
                    if (key > q) st[kb][rr] = -1e30f;
                }
        }

        // fixed-max softmax; Ps write at chunk-XOR swizzled column
        #pragma unroll
        for (int kb = 0; kb < 4; kb++) {
            bf16x4 pk;
            #pragma unroll
            for (int rr = 0; rr < 4; rr++) {
                float pv = exp2f(st[kb][rr]);
                l_lane += pv;
                pk[rr] = (bf16)pv;
            }
            int ch = kb * 2 + (quad >> 1);
            *(bf16x4*)&Ps[w][l15][((ch ^ lx7) << 3) + ((quad & 1) << 2)] = pk;
        }

        // O^T += V^T * P^T  (A = V^T rows d, B = P^T cols q)
        bf16x8 pb0 = *(const bf16x8*)&Ps[w][l15][(quad ^ lx7) << 3];
        bf16x8 pb1 = *(const bf16x8*)&Ps[w][l15][((quad + 4) ^ lx7) << 3];
        __builtin_amdgcn_s_setprio(1);
        #pragma unroll
        for (int nt = 0; nt < 4; nt++) {
            int row = nt * 16 + l15;
            int rx = row & 7;
            bf16x8 v0 = *(const bf16x8*)&Vt[buf][row][(quad ^ rx) * 8];
            bf16x8 v1 = *(const bf16x8*)&Vt[buf][row][((quad + 4) ^ rx) * 8];
            acc[nt] = MFMA16(v0, pb0, acc[nt]);
            acc[nt] = MFMA16(v1, pb1, acc[nt]);
        }
        __builtin_amdgcn_s_setprio(0);

        TRAIL_BAR();
    }

    // single cross-lane reduce: sum l over the 4 quads (same query l15)
    l_lane += __shfl_xor(l_lane, 16, 64);
    l_lane += __shfl_xor(l_lane, 32, 64);
    float inv = 1.f / l_lane;
    int s = qrow + l15;
    #pragma unroll
    for (int nt = 0; nt < 4; nt++) {
        bf16x4 pk;
        #pragma unroll
        for (int rr = 0; rr < 4; rr++) pk[rr] = (bf16)(acc[nt][rr] * inv);
        *(bf16x4*)&o_ws[((size_t)(bb * 2048 + s)) * 1024 + h * 64 + nt * 16 + quad * 4] = pk;
    }
}

// ---------------------------------------------------------------------------
extern "C" void kernel_launch(void* const* d_in, const int* in_sizes, int n_in,
                              void* d_out, int out_size, void* d_ws, size_t ws_size,
                              hipStream_t stream) {
    const float* x  = (const float*)d_in[0];
    const float* Wq = (const float*)d_in[1];
    const float* bq = (const float*)d_in[2];
    const float* Wk = (const float*)d_in[3];
    const float* bk = (const float*)d_in[4];
    const float* Wv = (const float*)d_in[5];
    const float* bv = (const float*)d_in[6];
    const float* Wo = (const float*)d_in[7];
    const float* bo = (const float*)d_in[8];
    float* out = (float*)d_out;

    const size_t NELEM = (size_t)2 * 2048 * 1024;   // 4,194,304
    const size_t WELEM = (size_t)1024 * 1024;
    bf16* xb    = (bf16*)d_ws;          // 8MB; reused as o_ws after qkv
    bf16* q_ws  = xb + NELEM;
    bf16* k_ws  = q_ws + NELEM;
    bf16* vt_ws = k_ws + NELEM;         // (B,NH,HD,S)
    bf16* o_ws  = xb;
    bf16* wqb   = vt_ws + NELEM;        // +2MB each
    bf16* wkb   = wqb + WELEM;
    bf16* wvb   = wkb + WELEM;
    bf16* wob   = wvb + WELEM;          // ends at 40MB

    bool fast = ws_size >= (size_t)40 * 1024 * 1024;   // constant across calls

    if (fast) {
        cvt_all_kernel<<<8192, 256, 0, stream>>>(x, Wq, Wk, Wv, Wo,
                                                 xb, wqb, wkb, wvb, wob);
        gemm_qkv_fast<<<dim3(32, 24), 256, 0, stream>>>(
            xb, wqb, wkb, wvb, bq, bk, bv, q_ws, k_ws, vt_ws);
        attn_kernel<<<1024, 256, 0, stream>>>(q_ws, k_ws, vt_ws, o_ws);
        gemm_out_fast<<<dim3(32, 8), 256, 0, stream>>>(o_ws, wob, bo, out);
    } else {
        cvt_kernel<<<4096, 256, 0, stream>>>(x, xb);
        gemm_qkv_f32w<<<dim3(32, 24), 256, 0, stream>>>(
            xb, Wq, Wk, Wv, bq, bk, bv, q_ws, k_ws, vt_ws);
        attn_kernel<<<1024, 256, 0, stream>>>(q_ws, k_ws, vt_ws, o_ws);
        gemm_out_f32w<<<dim3(32, 8), 256, 0, stream>>>(o_ws, Wo, bo, out);
    }
}